// Round 12
// baseline (117.990 us; speedup 1.0000x reference)
//
#include <hip/hip_runtime.h>
#include <hip/hip_bf16.h>
#include <cstdint>
#include <cmath>

#define BB 4
#define TT 2048
#define DD 512
#define RR 1024
#define MM (BB*RR)       // 4096
#define NBINS 13
#define LDXP (NBINS*DD)  // 6656

typedef __bf16 bf16;
typedef bf16 bf16x8 __attribute__((ext_vector_type(8)));
typedef float f32x4 __attribute__((ext_vector_type(4)));

__device__ __forceinline__ float selu_f(float x) {
    const float sc = 1.0507009873554805f;
    const float aa = 1.6732632423543772f;
    return x > 0.0f ? sc * x : sc * aa * (expf(x) - 1.0f);
}

__device__ __forceinline__ void gload_lds16(const bf16* g, bf16* l) {
    __builtin_amdgcn_global_load_lds(
        (const __attribute__((address_space(1))) void*)g,
        (__attribute__((address_space(3))) void*)l, 16, 0, 0);
}

template<int N>
__device__ __forceinline__ void wait_vm() {
    if constexpr (N == 0)      asm volatile("s_waitcnt vmcnt(0)" ::: "memory");
    else if constexpr (N == 3) asm volatile("s_waitcnt vmcnt(3)" ::: "memory");
    else if constexpr (N == 4) asm volatile("s_waitcnt vmcnt(4)" ::: "memory");
    else if constexpr (N == 6) asm volatile("s_waitcnt vmcnt(6)" ::: "memory");
    else if constexpr (N == 8) asm volatile("s_waitcnt vmcnt(8)" ::: "memory");
}

__device__ __forceinline__ void lgkm_fence() {
    asm volatile("s_waitcnt lgkmcnt(0)" ::: "memory");
    __builtin_amdgcn_sched_barrier(0);
}
__device__ __forceinline__ void barrier_pinned() {
    __builtin_amdgcn_s_barrier();
    __builtin_amdgcn_sched_barrier(0);
}

// Stage a [ROWS][32] bf16 tile into LDS, swizzled: physical 16B slot p of row
// r holds logical slot p ^ ((r>>1)&3).  LDS dest linear (global_load_lds
// writes wave-base + lane*16); source address carries the permutation.
// Correctness-proven in r9.
template<int ROWS>
__device__ __forceinline__ void stage32(const bf16* __restrict__ src, int lda,
                                        bf16* dst, int tid) {
#pragma unroll
    for (int it = 0; it < (ROWS * 4) / 256; ++it) {
        int idx = it * 256 + tid;
        int row = idx >> 2;                               // 4 slots of 16B per 64B row
        int col = ((idx & 3) ^ ((row >> 1) & 3)) * 8;
        bf16* wavebase = dst + (idx & ~63) * 8;           // wave-uniform base
        gload_lds16(src + (size_t)row * lda + col, wavebase);
    }
}

// Fragment read with the matching XOR (2 rows per bank-group start = ~free).
__device__ __forceinline__ bf16x8 frd32(const bf16* tile, int row, int sl) {
    int p = sl ^ ((row >> 1) & 3);
    return *(const bf16x8*)(tile + row * 32 + p * 8);
}

// ---------------- fused prep: pool + weight transforms ----------------
template<int NB_, int KT>
__device__ __forceinline__ void w_row_body(const float* __restrict__ Wsrc,
                                           bf16* __restrict__ Wdst,
                                           float* ld, int n, int tid) {
    const float* src = Wsrc + (size_t)n * KT;
    for (int i = tid; i < KT; i += 256) ld[i] = src[i];
    __syncthreads();
    bf16* dst = Wdst + (size_t)n * KT;
    for (int i = tid; i < KT; i += 256) {
        int bin = i >> 9, d = i & 511;
        dst[i] = (bf16)ld[d * NB_ + bin];
    }
}

// 256 threads: 64 threads x 8 d-values cover D=512; 4 bins concurrently.
__device__ __forceinline__ void pool_body(const float* __restrict__ feats,
                                          const float* __restrict__ rois,
                                          bf16* __restrict__ Xp, int m, int tid) {
    int b = m >> 10;
    float s = rois[2 * m];
    float e = rois[2 * m + 1];
    float ext = 0.2f * (e - s);
    int dd = (tid & 63) * 8;
    int j0 = tid >> 6;
    const float* fb = feats + (size_t)b * TT * DD + dd;
    bf16* orow = Xp + (size_t)m * LDXP + dd;
#pragma unroll
    for (int jj = 0; jj < 4; ++jj) {
        int j = j0 + jj * 4;
        if (j >= NBINS) break;
        float pos;
        if (j < 2)       pos = (s - ext) + ((float)j + 0.5f) * ext;
        else if (j < 11) pos = s + (((float)(j - 2) + 0.5f) * (1.0f / 9.0f)) * (e - s);
        else             pos = (e - ext) + ((float)(j - 11) + 0.5f) * ext;
        pos = fminf(fmaxf(pos, 0.0f), (float)(TT - 1));
        float fl = floorf(pos);
        int lo = (int)fl;
        int hi = lo + 1; if (hi > TT - 1) hi = TT - 1;
        float w = pos - fl;
        const float* rlo = fb + (size_t)lo * DD;
        const float* rhi = fb + (size_t)hi * DD;
        float4 l0 = *(const float4*)(rlo);
        float4 l1 = *(const float4*)(rlo + 4);
        float4 h0 = *(const float4*)(rhi);
        float4 h1 = *(const float4*)(rhi + 4);
        bf16x8 o;
        o[0] = (bf16)((1.0f - w) * l0.x + w * h0.x);
        o[1] = (bf16)((1.0f - w) * l0.y + w * h0.y);
        o[2] = (bf16)((1.0f - w) * l0.z + w * h0.z);
        o[3] = (bf16)((1.0f - w) * l0.w + w * h0.w);
        o[4] = (bf16)((1.0f - w) * l1.x + w * h1.x);
        o[5] = (bf16)((1.0f - w) * l1.y + w * h1.y);
        o[6] = (bf16)((1.0f - w) * l1.z + w * h1.z);
        o[7] = (bf16)((1.0f - w) * l1.w + w * h1.w);
        *(bf16x8*)(orow + j * DD) = o;
    }
}

__global__ __launch_bounds__(256) void prep_all(
    const float* __restrict__ feats, const float* __restrict__ rois,
    const float* __restrict__ W_left, const float* __restrict__ W_inner,
    const float* __restrict__ W_roi,
    bf16* __restrict__ Xp, bf16* __restrict__ Wl, bf16* __restrict__ Wi,
    bf16* __restrict__ Wr)
{
    __shared__ float ld[4608];
    int bid = blockIdx.x, tid = threadIdx.x;
    if (bid < 4096) {
        pool_body(feats, rois, Xp, bid, tid);
    } else if (bid < 4608) {
        w_row_body<7, 3584>(W_left, Wl, ld, bid - 4096, tid);
    } else if (bid < 5120) {
        w_row_body<9, 4608>(W_inner, Wi, ld, bid - 4608, tid);
    } else {
        int i0 = (bid - 5120) * 1024 + tid * 4;
        float4 v = *(const float4*)(W_roi + i0);
        bf16* d = Wr + i0;
        d[0] = (bf16)v.x; d[1] = (bf16)v.y; d[2] = (bf16)v.z; d[3] = (bf16)v.w;
    }
}

// ---------------- GEMM bodies: read-ahead pipeline ----------------
// BM=64, BN=128, BK=32; 256 threads = 4 waves (2x2), wave tile 32x64 (2x4).
// FOUR small LDS buffers; stage issued 3 tiles ahead; fragments for tile t+1
// read DURING tile t's MFMA into an alternate register set (static 2-unroll).
// Per step: vmcnt(counted) -> barrier -> stage(t+3) -> ds_read(t+1) ->
// MFMA(t) -> lgkmcnt(0).  ds_read latency and lgkm drain are covered by the
// MFMA cluster; vmcnt targets loads issued 2 steps earlier and never drains
// to 0 mid-loop.
// Safety: vmcnt precedes the barrier, so barrier release certifies ALL waves'
// stage(t+1) DMA complete.  stage(t+3) writes buf((t+3)&3)=buf(t-1), whose
// last readers (frags(t-1), read in body t-2, retired by that body's lgkm)
// are >= 2 barriers upstream.

template<int K, bool OUT_BF16>
__device__ __forceinline__ void gemm_single_body(
    const bf16* __restrict__ A, int lda,
    const bf16* __restrict__ Bw, const float* __restrict__ bias,
    void* __restrict__ Out, int ldo, int ocol0,
    bf16* sm, int m0, int n0)
{
    int tid = threadIdx.x, lane = tid & 63, w = tid >> 6;
    int wr = w >> 1, wc = w & 1;
    const bf16* Ab = A + (size_t)m0 * lda;
    const bf16* Bb = Bw + (size_t)n0 * K;
    int frow = lane & 15, sl = lane >> 4;
    f32x4 acc[2][4] = {};
    // buffer u: A at u*6144, B at u*6144+2048  (12 KB each, 48 KB total)

    auto stage = [&](int u) {                    // 3 loads/thread
        bf16* p = sm + (u & 3) * 6144;
        stage32<64>(Ab + u * 32, lda, p, tid);
        stage32<128>(Bb + u * 32, K, p + 2048, tid);
    };
    bf16x8 fA[2][2], fB[2][4];
    auto readf = [&](int u, int s) {
        bf16* p = sm + (u & 3) * 6144;
#pragma unroll
        for (int mf = 0; mf < 2; ++mf) fA[s][mf] = frd32(p, wr * 32 + mf * 16 + frow, sl);
#pragma unroll
        for (int nf = 0; nf < 4; ++nf) fB[s][nf] = frd32(p + 2048, wc * 64 + nf * 16 + frow, sl);
    };
    auto mma = [&](int s) {
        __builtin_amdgcn_s_setprio(1);
#pragma unroll
        for (int mf = 0; mf < 2; ++mf)
#pragma unroll
            for (int nf = 0; nf < 4; ++nf)
                acc[mf][nf] = __builtin_amdgcn_mfma_f32_16x16x32_bf16(fA[s][mf], fB[s][nf], acc[mf][nf], 0, 0, 0);
        __builtin_amdgcn_s_setprio(0);
    };

    constexpr int NT = K / 32;                   // 144 / 32
    auto body = [&](int t, int cs, int fs) {
        if (t + 2 < NT) wait_vm<3>(); else wait_vm<0>();
        barrier_pinned();
        if (t + 3 < NT) stage(t + 3);
        if (t + 1 < NT) readf(t + 1, fs);
        mma(cs);
        lgkm_fence();
    };

    stage(0); stage(1); stage(2);
    wait_vm<6>();
    barrier_pinned();
    readf(0, 0);
    lgkm_fence();
    for (int t = 0; t < NT; t += 2) {
        body(t, 0, 1);
        body(t + 1, 1, 0);
    }

    int crow = (lane >> 4) * 4;
    int ccol = lane & 15;
#pragma unroll
    for (int mf = 0; mf < 2; ++mf) {
#pragma unroll
        for (int nf = 0; nf < 4; ++nf) {
            int col = n0 + wc * 64 + nf * 16 + ccol;
            float bv = bias[col];
#pragma unroll
            for (int r2 = 0; r2 < 4; ++r2) {
                int row = m0 + wr * 32 + mf * 16 + crow + r2;
                float v = selu_f(acc[mf][nf][r2] + bv);
                if constexpr (OUT_BF16)
                    ((bf16*)Out)[(size_t)row * ldo + ocol0 + col] = (bf16)v;
                else
                    ((float*)Out)[(size_t)row * ldo + ocol0 + col] = v;
            }
        }
    }
}

template<int K>
__device__ __forceinline__ void gemm_dual_body(
    const bf16* __restrict__ Xp, const bf16* __restrict__ Wl,
    const float* __restrict__ bias, bf16* __restrict__ Y,
    bf16* sm, int m0, int n0)
{
    int tid = threadIdx.x, lane = tid & 63, w = tid >> 6;
    int wr = w >> 1, wc = w & 1;
    const bf16* AL = Xp + (size_t)m0 * LDXP;         // bins 0..6
    const bf16* AR = AL + 3072;                      // bins 6..12
    const bf16* Bb = Wl + (size_t)n0 * K;
    int frow = lane & 15, sl = lane >> 4;
    f32x4 accL[2][4] = {}, accR[2][4] = {};
    // buffer u: L at u*8192, R at +2048, B at +4096  (16 KB each, 64 KB total)

    auto stage = [&](int u) {                    // 4 loads/thread
        bf16* p = sm + (u & 3) * 8192;
        stage32<64>(AL + u * 32, LDXP, p, tid);
        stage32<64>(AR + u * 32, LDXP, p + 2048, tid);
        stage32<128>(Bb + u * 32, K, p + 4096, tid);
    };
    bf16x8 fL[2][2], fR[2][2], fB[2][4];
    auto readf = [&](int u, int s) {
        bf16* p = sm + (u & 3) * 8192;
#pragma unroll
        for (int mf = 0; mf < 2; ++mf) {
            fL[s][mf] = frd32(p, wr * 32 + mf * 16 + frow, sl);
            fR[s][mf] = frd32(p + 2048, wr * 32 + mf * 16 + frow, sl);
        }
#pragma unroll
        for (int nf = 0; nf < 4; ++nf)
            fB[s][nf] = frd32(p + 4096, wc * 64 + nf * 16 + frow, sl);
    };
    auto mma = [&](int s) {
        __builtin_amdgcn_s_setprio(1);
#pragma unroll
        for (int mf = 0; mf < 2; ++mf)
#pragma unroll
            for (int nf = 0; nf < 4; ++nf) {
                accL[mf][nf] = __builtin_amdgcn_mfma_f32_16x16x32_bf16(fL[s][mf], fB[s][nf], accL[mf][nf], 0, 0, 0);
                accR[mf][nf] = __builtin_amdgcn_mfma_f32_16x16x32_bf16(fR[s][mf], fB[s][nf], accR[mf][nf], 0, 0, 0);
            }
        __builtin_amdgcn_s_setprio(0);
    };

    constexpr int NT = K / 32;                   // 112
    auto body = [&](int t, int cs, int fs) {
        if (t + 2 < NT) wait_vm<4>(); else wait_vm<0>();
        barrier_pinned();
        if (t + 3 < NT) stage(t + 3);
        if (t + 1 < NT) readf(t + 1, fs);
        mma(cs);
        lgkm_fence();
    };

    stage(0); stage(1); stage(2);
    wait_vm<8>();
    barrier_pinned();
    readf(0, 0);
    lgkm_fence();
    for (int t = 0; t < NT; t += 2) {
        body(t, 0, 1);
        body(t + 1, 1, 0);
    }

    int crow = (lane >> 4) * 4;
    int ccol = lane & 15;
#pragma unroll
    for (int mf = 0; mf < 2; ++mf) {
#pragma unroll
        for (int nf = 0; nf < 4; ++nf) {
            int col = n0 + wc * 64 + nf * 16 + ccol;
            float bv = bias[col];
#pragma unroll
            for (int r2 = 0; r2 < 4; ++r2) {
                int row = m0 + wr * 32 + mf * 16 + crow + r2;
                float vL = selu_f(accL[mf][nf][r2] + bv);
                float vR = selu_f(accR[mf][nf][r2] + bv);
                Y[(size_t)row * 1024 + col] = (bf16)(vR - vL);
            }
        }
    }
}

// ---------------- GEMM kernels ----------------
// Linear m-major mapping (measured best): dual bids 0..255, inner 256..511.
// LDS 64 KB (dual) / 48 KB (inner) -> 2 blocks/CU (cross-block covering).
__global__ __launch_bounds__(256) void wide_gemm(
    const bf16* __restrict__ Xp, const bf16* __restrict__ Wl,
    const float* __restrict__ bl, const bf16* __restrict__ Wi,
    const float* __restrict__ bi, bf16* __restrict__ Y)
{
    __shared__ bf16 sm[32768];  // 64 KB: 4 buffers x 16 KB (dual); inner uses 48 KB
    int bid = blockIdx.x;
    if (bid < 256) {
        gemm_dual_body<3584>(Xp, Wl, bl, Y, sm, (bid & 63) * 64, (bid >> 6) * 128);
    } else {
        int b2 = bid - 256;
        gemm_single_body<4608, true>(Xp + 1024, LDXP, Wi, bi, (void*)Y, 1024, 512,
                                     sm, (b2 & 63) * 64, (b2 >> 6) * 128);
    }
}

__global__ __launch_bounds__(256) void final_gemm(
    const bf16* __restrict__ Y, const bf16* __restrict__ Wr,
    const float* __restrict__ br, float* __restrict__ out)
{
    __shared__ bf16 sm[24576];  // 48 KB: 4 buffers x 12 KB
    int bid = blockIdx.x;
    gemm_single_body<1024, false>(Y, 1024, Wr, br, (void*)out, 512, 0,
                                  sm, (bid & 63) * 64, (bid >> 6) * 128);
}

// ---------------- launch ----------------
extern "C" void kernel_launch(void* const* d_in, const int* in_sizes, int n_in,
                              void* d_out, int out_size, void* d_ws, size_t ws_size,
                              hipStream_t stream) {
    const float* feats   = (const float*)d_in[0];
    const float* rois    = (const float*)d_in[3];
    const float* W_left  = (const float*)d_in[6];
    const float* b_left  = (const float*)d_in[7];
    const float* W_inner = (const float*)d_in[8];
    const float* b_inner = (const float*)d_in[9];
    const float* W_roi   = (const float*)d_in[10];
    const float* b_roi   = (const float*)d_in[11];
    float* out = (float*)d_out;

    bf16* wsb = (bf16*)d_ws;
    constexpr size_t XP_ELEMS = (size_t)MM * LDXP;
    constexpr size_t WL_ELEMS = (size_t)512 * 3584;
    constexpr size_t WI_ELEMS = (size_t)512 * 4608;
    constexpr size_t WR_ELEMS = (size_t)512 * 1024;
    bf16* Xp = wsb;
    bf16* Wl = Xp + XP_ELEMS;
    bf16* Wi = Wl + WL_ELEMS;
    bf16* Wr = Wi + WI_ELEMS;
    bf16* Y  = Wr + WR_ELEMS;   // [M][1024]

    prep_all<<<5632, 256, 0, stream>>>(feats, rois, W_left, W_inner, W_roi,
                                       Xp, Wl, Wi, Wr);
    wide_gemm<<<512, 256, 0, stream>>>(Xp, Wl, b_left, Wi, b_inner, Y);
    final_gemm<<<256, 256, 0, stream>>>(Y, Wr, b_roi, out);
}

// Round 13
// 99.741 us; speedup vs baseline: 1.1830x; 1.1830x over previous
//
#include <hip/hip_runtime.h>
#include <hip/hip_bf16.h>
#include <cstdint>
#include <cmath>

#define BB 4
#define TT 2048
#define DD 512
#define RR 1024
#define MM (BB*RR)       // 4096
#define NBINS 13
#define LDXP (NBINS*DD)  // 6656

typedef __bf16 bf16;
typedef bf16 bf16x8 __attribute__((ext_vector_type(8)));
typedef float f32x4 __attribute__((ext_vector_type(4)));

__device__ __forceinline__ float selu_f(float x) {
    const float sc = 1.0507009873554805f;
    const float aa = 1.6732632423543772f;
    return x > 0.0f ? sc * x : sc * aa * (expf(x) - 1.0f);
}

__device__ __forceinline__ void gload_lds16(const bf16* g, bf16* l) {
    __builtin_amdgcn_global_load_lds(
        (const __attribute__((address_space(1))) void*)g,
        (__attribute__((address_space(3))) void*)l, 16, 0, 0);
}

template<int N>
__device__ __forceinline__ void wait_vm() {
    if constexpr (N == 0)      asm volatile("s_waitcnt vmcnt(0)" ::: "memory");
    else if constexpr (N == 6) asm volatile("s_waitcnt vmcnt(6)" ::: "memory");
    else if constexpr (N == 8) asm volatile("s_waitcnt vmcnt(8)" ::: "memory");
}

// Stage a [ROWS][64] bf16 tile into LDS, XOR-swizzled: physical 16B slot p of
// row r holds logical slot p ^ (r&7).  LDS dest stays linear (global_load_lds
// writes wave-base + lane*16); the source address carries the permutation.
template<int ROWS>
__device__ __forceinline__ void stage_tile64(const bf16* __restrict__ src, int lda,
                                             bf16* tile, int tid) {
#pragma unroll
    for (int it = 0; it < ROWS / 32; ++it) {     // 256 threads cover 32 rows/iter
        int idx = it * 256 + tid;
        int row = idx >> 3;                       // 8 slots of 16B per 128B row
        int col = ((idx & 7) ^ (row & 7)) * 8;
        bf16* wavebase = tile + (idx & ~63) * 8;  // wave-uniform base
        gload_lds16(src + (size_t)row * lda + col, wavebase);
    }
}

// Fragment read with the matching XOR (2-way bank alias = free).
__device__ __forceinline__ bf16x8 frd64(const bf16* tile, int row, int s) {
    int p = s ^ (row & 7);
    return *(const bf16x8*)(tile + row * 64 + p * 8);
}

// ---------------- fused prep: pool + weight transforms ----------------
template<int NB_, int KT>
__device__ __forceinline__ void w_row_body(const float* __restrict__ Wsrc,
                                           bf16* __restrict__ Wdst,
                                           float* ld, int n, int tid) {
    const float* src = Wsrc + (size_t)n * KT;
    for (int i = tid; i < KT; i += 256) ld[i] = src[i];
    __syncthreads();
    bf16* dst = Wdst + (size_t)n * KT;
    for (int i = tid; i < KT; i += 256) {
        int bin = i >> 9, d = i & 511;
        dst[i] = (bf16)ld[d * NB_ + bin];
    }
}

// 256 threads: 64 threads x 8 d-values cover D=512; 4 bins concurrently.
__device__ __forceinline__ void pool_body(const float* __restrict__ feats,
                                          const float* __restrict__ rois,
                                          bf16* __restrict__ Xp, int m, int tid) {
    int b = m >> 10;
    float s = rois[2 * m];
    float e = rois[2 * m + 1];
    float ext = 0.2f * (e - s);
    int dd = (tid & 63) * 8;
    int j0 = tid >> 6;
    const float* fb = feats + (size_t)b * TT * DD + dd;
    bf16* orow = Xp + (size_t)m * LDXP + dd;
#pragma unroll
    for (int jj = 0; jj < 4; ++jj) {
        int j = j0 + jj * 4;
        if (j >= NBINS) break;
        float pos;
        if (j < 2)       pos = (s - ext) + ((float)j + 0.5f) * ext;
        else if (j < 11) pos = s + (((float)(j - 2) + 0.5f) * (1.0f / 9.0f)) * (e - s);
        else             pos = (e - ext) + ((float)(j - 11) + 0.5f) * ext;
        pos = fminf(fmaxf(pos, 0.0f), (float)(TT - 1));
        float fl = floorf(pos);
        int lo = (int)fl;
        int hi = lo + 1; if (hi > TT - 1) hi = TT - 1;
        float w = pos - fl;
        const float* rlo = fb + (size_t)lo * DD;
        const float* rhi = fb + (size_t)hi * DD;
        float4 l0 = *(const float4*)(rlo);
        float4 l1 = *(const float4*)(rlo + 4);
        float4 h0 = *(const float4*)(rhi);
        float4 h1 = *(const float4*)(rhi + 4);
        bf16x8 o;
        o[0] = (bf16)((1.0f - w) * l0.x + w * h0.x);
        o[1] = (bf16)((1.0f - w) * l0.y + w * h0.y);
        o[2] = (bf16)((1.0f - w) * l0.z + w * h0.z);
        o[3] = (bf16)((1.0f - w) * l0.w + w * h0.w);
        o[4] = (bf16)((1.0f - w) * l1.x + w * h1.x);
        o[5] = (bf16)((1.0f - w) * l1.y + w * h1.y);
        o[6] = (bf16)((1.0f - w) * l1.z + w * h1.z);
        o[7] = (bf16)((1.0f - w) * l1.w + w * h1.w);
        *(bf16x8*)(orow + j * DD) = o;
    }
}

__global__ __launch_bounds__(256) void prep_all(
    const float* __restrict__ feats, const float* __restrict__ rois,
    const float* __restrict__ W_left, const float* __restrict__ W_inner,
    const float* __restrict__ W_roi,
    bf16* __restrict__ Xp, bf16* __restrict__ Wl, bf16* __restrict__ Wi,
    bf16* __restrict__ Wr)
{
    __shared__ float ld[4608];
    int bid = blockIdx.x, tid = threadIdx.x;
    if (bid < 4096) {
        pool_body(feats, rois, Xp, bid, tid);
    } else if (bid < 4608) {
        w_row_body<7, 3584>(W_left, Wl, ld, bid - 4096, tid);
    } else if (bid < 5120) {
        w_row_body<9, 4608>(W_inner, Wi, ld, bid - 4608, tid);
    } else {
        int i0 = (bid - 5120) * 1024 + tid * 4;
        float4 v = *(const float4*)(W_roi + i0);
        bf16* d = Wr + i0;
        d[0] = (bf16)v.x; d[1] = (bf16)v.y; d[2] = (bf16)v.z; d[3] = (bf16)v.w;
    }
}

// ---------------- single GEMM body (r11 proven, unchanged) ----------------
template<int K, bool OUT_BF16>
__device__ __forceinline__ void gemm_single_body(
    const bf16* __restrict__ A, int lda,
    const bf16* __restrict__ Bw, const float* __restrict__ bias,
    void* __restrict__ Out, int ldo, int ocol0,
    bf16* sm, int m0, int n0)
{
    int tid = threadIdx.x, lane = tid & 63, w = tid >> 6;
    int wr = w >> 1, wc = w & 1;
    const bf16* Ab = A + (size_t)m0 * lda;
    const bf16* Bb = Bw + (size_t)n0 * K;
    int frow = lane & 15, sl = lane >> 4;
    f32x4 acc[2][4] = {};
    bf16 *A0 = sm,         *B0 = sm + 4096;
    bf16 *A1 = sm + 12288, *B1 = sm + 12288 + 4096;

    auto stage = [&](bf16* as, bf16* bs, int t) {   // 6 loads/thread
        stage_tile64<64>(Ab + t * 64, lda, as, tid);
        stage_tile64<128>(Bb + t * 64, K, bs, tid);
    };
    auto step_body = [&](bf16* as, bf16* bs, int t, bool dostage) {
        __builtin_amdgcn_s_barrier();
        bf16x8 af[2][2], bfr[2][4];
#pragma unroll
        for (int ks = 0; ks < 2; ++ks) {
#pragma unroll
            for (int mf = 0; mf < 2; ++mf) af[ks][mf] = frd64(as, wr * 32 + mf * 16 + frow, ks * 4 + sl);
#pragma unroll
            for (int nf = 0; nf < 4; ++nf) bfr[ks][nf] = frd64(bs, wc * 64 + nf * 16 + frow, ks * 4 + sl);
        }
        asm volatile("s_waitcnt lgkmcnt(0)" ::: "memory");
        __builtin_amdgcn_sched_barrier(0);
        __builtin_amdgcn_s_barrier();
        if (dostage) stage(as, bs, t + 2);
        __builtin_amdgcn_s_setprio(1);
#pragma unroll
        for (int ks = 0; ks < 2; ++ks)
#pragma unroll
            for (int mf = 0; mf < 2; ++mf)
#pragma unroll
                for (int nf = 0; nf < 4; ++nf)
                    acc[mf][nf] = __builtin_amdgcn_mfma_f32_16x16x32_bf16(af[ks][mf], bfr[ks][nf], acc[mf][nf], 0, 0, 0);
        __builtin_amdgcn_s_setprio(0);
    };

    constexpr int NT = K / 64;
    stage(A0, B0, 0);
    stage(A1, B1, 1);
    for (int t = 0; t + 2 < NT; t += 2) {
        wait_vm<6>(); step_body(A0, B0, t, true);
        wait_vm<6>(); step_body(A1, B1, t + 1, true);
    }
    wait_vm<6>(); step_body(A0, B0, NT - 2, false);
    wait_vm<0>(); step_body(A1, B1, NT - 1, false);

    int crow = (lane >> 4) * 4;
    int ccol = lane & 15;
#pragma unroll
    for (int mf = 0; mf < 2; ++mf) {
#pragma unroll
        for (int nf = 0; nf < 4; ++nf) {
            int col = n0 + wc * 64 + nf * 16 + ccol;
            float bv = bias[col];
#pragma unroll
            for (int r2 = 0; r2 < 4; ++r2) {
                int row = m0 + wr * 32 + mf * 16 + crow + r2;
                float v = selu_f(acc[mf][nf][r2] + bv);
                if constexpr (OUT_BF16)
                    ((bf16*)Out)[(size_t)row * ldo + ocol0 + col] = (bf16)v;
                else
                    ((float*)Out)[(size_t)row * ldo + ocol0 + col] = v;
            }
        }
    }
}

// ---------------- dual GEMM body: in-wave L/R stream interleave ----------------
// BM=64, BN=128, BK=64; 4 waves (2x2), wave tile 32x64.  Two phases per K-tile:
//   A(t): vm(8) -> bar -> readB(t)+readL(t) -> MFMA_R(t-1) -> lgkm -> bar -> stageL(t+2)
//   B(t):                 readR(t)          -> MFMA_L(t)   -> lgkm -> bar -> stageRB(t+2)
// Each stream's MFMA covers the other stream's ds_read issue/latency IN-ORDER
// (no scheduler luck).  vmcnt induction: before each A-wait outstanding =
// {L(t)[2], RB(t)[6], L(t+1)[2], RB(t+1)[6]} = 16 -> vmcnt(8) retires exactly
// tile t; B-phase needs NO vm wait (R(t) retired with RB(t)).  Stage targets
// are one-lgkm+barrier past their last readers (r10/r11 discipline).
template<int K>
__device__ __forceinline__ void gemm_dual_body(
    const bf16* __restrict__ Xp, const bf16* __restrict__ Wl,
    const float* __restrict__ bias, bf16* __restrict__ Y,
    bf16* sm, int m0, int n0)
{
    int tid = threadIdx.x, lane = tid & 63, w = tid >> 6;
    int wr = w >> 1, wc = w & 1;
    const bf16* AL = Xp + (size_t)m0 * LDXP;         // bins 0..6
    const bf16* AR = AL + 3072;                      // bins 6..12
    const bf16* Bb = Wl + (size_t)n0 * K;
    int frow = lane & 15, sl = lane >> 4;
    f32x4 accL[2][4] = {}, accR[2][4] = {};
    bf16 *Ls[2] = {sm,         sm + 4096};
    bf16 *Rs[2] = {sm + 8192,  sm + 12288};
    bf16 *Bs[2] = {sm + 16384, sm + 24576};

    bf16x8 fL[2][2][2], fR[2][2][2], fB[2][2][4];    // [set][ks][frag]

    auto stageL  = [&](int t) {                      // 2 loads/thread
        stage_tile64<64>(AL + t * 64, LDXP, Ls[t & 1], tid);
    };
    auto stageRB = [&](int t) {                      // 6 loads/thread
        stage_tile64<64>(AR + t * 64, LDXP, Rs[t & 1], tid);
        stage_tile64<128>(Bb + t * 64, K, Bs[t & 1], tid);
    };
    auto readLB = [&](int t, int s) {                // 12 ds_reads
#pragma unroll
        for (int ks = 0; ks < 2; ++ks) {
#pragma unroll
            for (int nf = 0; nf < 4; ++nf)
                fB[s][ks][nf] = frd64(Bs[t & 1], wc * 64 + nf * 16 + frow, ks * 4 + sl);
#pragma unroll
            for (int mf = 0; mf < 2; ++mf)
                fL[s][ks][mf] = frd64(Ls[t & 1], wr * 32 + mf * 16 + frow, ks * 4 + sl);
        }
    };
    auto readR = [&](int t, int s) {                 // 4 ds_reads
#pragma unroll
        for (int ks = 0; ks < 2; ++ks)
#pragma unroll
            for (int mf = 0; mf < 2; ++mf)
                fR[s][ks][mf] = frd64(Rs[t & 1], wr * 32 + mf * 16 + frow, ks * 4 + sl);
    };
    auto mmaR = [&](int s) {
        __builtin_amdgcn_s_setprio(1);
#pragma unroll
        for (int ks = 0; ks < 2; ++ks)
#pragma unroll
            for (int mf = 0; mf < 2; ++mf)
#pragma unroll
                for (int nf = 0; nf < 4; ++nf)
                    accR[mf][nf] = __builtin_amdgcn_mfma_f32_16x16x32_bf16(fR[s][ks][mf], fB[s][ks][nf], accR[mf][nf], 0, 0, 0);
        __builtin_amdgcn_s_setprio(0);
    };
    auto mmaL = [&](int s) {
        __builtin_amdgcn_s_setprio(1);
#pragma unroll
        for (int ks = 0; ks < 2; ++ks)
#pragma unroll
            for (int mf = 0; mf < 2; ++mf)
#pragma unroll
                for (int nf = 0; nf < 4; ++nf)
                    accL[mf][nf] = __builtin_amdgcn_mfma_f32_16x16x32_bf16(fL[s][ks][mf], fB[s][ks][nf], accL[mf][nf], 0, 0, 0);
        __builtin_amdgcn_s_setprio(0);
    };

    constexpr int NT = K / 64;   // 56 (even)
    stageL(0); stageRB(0); stageL(1); stageRB(1);

    for (int t = 0; t < NT; t += 2) {
        // ---- parity 0: phase A ----
        if (t + 1 < NT) wait_vm<8>(); else wait_vm<0>();
        __builtin_amdgcn_s_barrier();
        readLB(t, 0);
        if (t > 0) mmaR(1);
        asm volatile("s_waitcnt lgkmcnt(0)" ::: "memory");
        __builtin_amdgcn_s_barrier();
        if (t + 2 < NT) stageL(t + 2);
        // ---- parity 0: phase B ----
        readR(t, 0);
        mmaL(0);
        asm volatile("s_waitcnt lgkmcnt(0)" ::: "memory");
        __builtin_amdgcn_s_barrier();
        if (t + 2 < NT) stageRB(t + 2);
        // ---- parity 1: phase A ----
        int t1 = t + 1;
        if (t1 + 1 < NT) wait_vm<8>(); else wait_vm<0>();
        __builtin_amdgcn_s_barrier();
        readLB(t1, 1);
        mmaR(0);
        asm volatile("s_waitcnt lgkmcnt(0)" ::: "memory");
        __builtin_amdgcn_s_barrier();
        if (t1 + 2 < NT) stageL(t1 + 2);
        // ---- parity 1: phase B ----
        readR(t1, 1);
        mmaL(1);
        asm volatile("s_waitcnt lgkmcnt(0)" ::: "memory");
        __builtin_amdgcn_s_barrier();
        if (t1 + 2 < NT) stageRB(t1 + 2);
    }
    mmaR(1);   // finish tile NT-1 (set (NT-1)&1 = 1)

    int crow = (lane >> 4) * 4;
    int ccol = lane & 15;
#pragma unroll
    for (int mf = 0; mf < 2; ++mf) {
#pragma unroll
        for (int nf = 0; nf < 4; ++nf) {
            int col = n0 + wc * 64 + nf * 16 + ccol;
            float bv = bias[col];
#pragma unroll
            for (int r2 = 0; r2 < 4; ++r2) {
                int row = m0 + wr * 32 + mf * 16 + crow + r2;
                float vL = selu_f(accL[mf][nf][r2] + bv);
                float vR = selu_f(accR[mf][nf][r2] + bv);
                Y[(size_t)row * 1024 + col] = (bf16)(vR - vL);
            }
        }
    }
}

// ---------------- GEMM kernels ----------------
// Linear m-major mapping (measured best): dual bids 0..255, inner 256..511.
__global__ __launch_bounds__(256, 2) void wide_gemm(
    const bf16* __restrict__ Xp, const bf16* __restrict__ Wl,
    const float* __restrict__ bl, const bf16* __restrict__ Wi,
    const float* __restrict__ bi, bf16* __restrict__ Y)
{
    __shared__ bf16 sm[32768];  // 64 KB
    int bid = blockIdx.x;
    if (bid < 256) {
        gemm_dual_body<3584>(Xp, Wl, bl, Y, sm, (bid & 63) * 64, (bid >> 6) * 128);
    } else {
        int b2 = bid - 256;
        gemm_single_body<4608, true>(Xp + 1024, LDXP, Wi, bi, (void*)Y, 1024, 512,
                                     sm, (b2 & 63) * 64, (b2 >> 6) * 128);
    }
}

__global__ __launch_bounds__(256) void final_gemm(
    const bf16* __restrict__ Y, const bf16* __restrict__ Wr,
    const float* __restrict__ br, float* __restrict__ out)
{
    __shared__ bf16 sm[24576];  // 48 KB
    int bid = blockIdx.x;
    gemm_single_body<1024, false>(Y, 1024, Wr, br, (void*)out, 512, 0,
                                  sm, (bid & 63) * 64, (bid >> 6) * 128);
}

// ---------------- launch ----------------
extern "C" void kernel_launch(void* const* d_in, const int* in_sizes, int n_in,
                              void* d_out, int out_size, void* d_ws, size_t ws_size,
                              hipStream_t stream) {
    const float* feats   = (const float*)d_in[0];
    const float* rois    = (const float*)d_in[3];
    const float* W_left  = (const float*)d_in[6];
    const float* b_left  = (const float*)d_in[7];
    const float* W_inner = (const float*)d_in[8];
    const float* b_inner = (const float*)d_in[9];
    const float* W_roi   = (const float*)d_in[10];
    const float* b_roi   = (const float*)d_in[11];
    float* out = (float*)d_out;

    bf16* wsb = (bf16*)d_ws;
    constexpr size_t XP_ELEMS = (size_t)MM * LDXP;
    constexpr size_t WL_ELEMS = (size_t)512 * 3584;
    constexpr size_t WI_ELEMS = (size_t)512 * 4608;
    constexpr size_t WR_ELEMS = (size_t)512 * 1024;
    bf16* Xp = wsb;
    bf16* Wl = Xp + XP_ELEMS;
    bf16* Wi = Wl + WL_ELEMS;
    bf16* Wr = Wi + WI_ELEMS;
    bf16* Y  = Wr + WR_ELEMS;   // [M][1024]

    prep_all<<<5632, 256, 0, stream>>>(feats, rois, W_left, W_inner, W_roi,
                                       Xp, Wl, Wi, Wr);
    wide_gemm<<<512, 256, 0, stream>>>(Xp, Wl, b_left, Wi, b_inner, Y);
    final_gemm<<<256, 256, 0, stream>>>(Y, Wr, b_roi, out);
}

// Round 14
// 99.620 us; speedup vs baseline: 1.1844x; 1.0012x over previous
//
#include <hip/hip_runtime.h>
#include <hip/hip_bf16.h>
#include <cstdint>
#include <cmath>

#define BB 4
#define TT 2048
#define DD 512
#define RR 1024
#define MM (BB*RR)       // 4096
#define NBINS 13
#define LDXP (NBINS*DD)  // 6656

typedef __bf16 bf16;
typedef bf16 bf16x8 __attribute__((ext_vector_type(8)));
typedef float f32x4 __attribute__((ext_vector_type(4)));

__device__ __forceinline__ float selu_f(float x) {
    const float sc = 1.0507009873554805f;
    const float aa = 1.6732632423543772f;
    return x > 0.0f ? sc * x : sc * aa * (expf(x) - 1.0f);
}

__device__ __forceinline__ void gload_lds16(const bf16* g, bf16* l) {
    __builtin_amdgcn_global_load_lds(
        (const __attribute__((address_space(1))) void*)g,
        (__attribute__((address_space(3))) void*)l, 16, 0, 0);
}

template<int N>
__device__ __forceinline__ void wait_vm() {
    if constexpr (N == 0)      asm volatile("s_waitcnt vmcnt(0)" ::: "memory");
    else if constexpr (N == 4) asm volatile("s_waitcnt vmcnt(4)" ::: "memory");
    else if constexpr (N == 6) asm volatile("s_waitcnt vmcnt(6)" ::: "memory");
    else if constexpr (N == 8) asm volatile("s_waitcnt vmcnt(8)" ::: "memory");
}

// Stage a [ROWS][64] bf16 tile into LDS, XOR-swizzled: physical 16B slot p of
// row r holds logical slot p ^ (r&7).  LDS dest stays linear (global_load_lds
// writes wave-base + lane*16); the source address carries the permutation.
template<int ROWS>
__device__ __forceinline__ void stage_tile64(const bf16* __restrict__ src, int lda,
                                             bf16* tile, int tid) {
#pragma unroll
    for (int it = 0; it < ROWS / 32; ++it) {     // 256 threads cover 32 rows/iter
        int idx = it * 256 + tid;
        int row = idx >> 3;                       // 8 slots of 16B per 128B row
        int col = ((idx & 7) ^ (row & 7)) * 8;
        bf16* wavebase = tile + (idx & ~63) * 8;  // wave-uniform base
        gload_lds16(src + (size_t)row * lda + col, wavebase);
    }
}

// Fragment read with the matching XOR (2-way bank alias = free).
__device__ __forceinline__ bf16x8 frd64(const bf16* tile, int row, int s) {
    int p = s ^ (row & 7);
    return *(const bf16x8*)(tile + row * 64 + p * 8);
}

// ---------------- fused prep: pool + weight transforms ----------------
template<int NB_, int KT>
__device__ __forceinline__ void w_row_body(const float* __restrict__ Wsrc,
                                           bf16* __restrict__ Wdst,
                                           float* ld, int n, int tid) {
    const float* src = Wsrc + (size_t)n * KT;
    for (int i = tid; i < KT; i += 256) ld[i] = src[i];
    __syncthreads();
    bf16* dst = Wdst + (size_t)n * KT;
    for (int i = tid; i < KT; i += 256) {
        int bin = i >> 9, d = i & 511;
        dst[i] = (bf16)ld[d * NB_ + bin];
    }
}

// 256 threads: 64 threads x 8 d-values cover D=512; 4 bins concurrently.
__device__ __forceinline__ void pool_body(const float* __restrict__ feats,
                                          const float* __restrict__ rois,
                                          bf16* __restrict__ Xp, int m, int tid) {
    int b = m >> 10;
    float s = rois[2 * m];
    float e = rois[2 * m + 1];
    float ext = 0.2f * (e - s);
    int dd = (tid & 63) * 8;
    int j0 = tid >> 6;
    const float* fb = feats + (size_t)b * TT * DD + dd;
    bf16* orow = Xp + (size_t)m * LDXP + dd;
#pragma unroll
    for (int jj = 0; jj < 4; ++jj) {
        int j = j0 + jj * 4;
        if (j >= NBINS) break;
        float pos;
        if (j < 2)       pos = (s - ext) + ((float)j + 0.5f) * ext;
        else if (j < 11) pos = s + (((float)(j - 2) + 0.5f) * (1.0f / 9.0f)) * (e - s);
        else             pos = (e - ext) + ((float)(j - 11) + 0.5f) * ext;
        pos = fminf(fmaxf(pos, 0.0f), (float)(TT - 1));
        float fl = floorf(pos);
        int lo = (int)fl;
        int hi = lo + 1; if (hi > TT - 1) hi = TT - 1;
        float w = pos - fl;
        const float* rlo = fb + (size_t)lo * DD;
        const float* rhi = fb + (size_t)hi * DD;
        float4 l0 = *(const float4*)(rlo);
        float4 l1 = *(const float4*)(rlo + 4);
        float4 h0 = *(const float4*)(rhi);
        float4 h1 = *(const float4*)(rhi + 4);
        bf16x8 o;
        o[0] = (bf16)((1.0f - w) * l0.x + w * h0.x);
        o[1] = (bf16)((1.0f - w) * l0.y + w * h0.y);
        o[2] = (bf16)((1.0f - w) * l0.z + w * h0.z);
        o[3] = (bf16)((1.0f - w) * l0.w + w * h0.w);
        o[4] = (bf16)((1.0f - w) * l1.x + w * h1.x);
        o[5] = (bf16)((1.0f - w) * l1.y + w * h1.y);
        o[6] = (bf16)((1.0f - w) * l1.z + w * h1.z);
        o[7] = (bf16)((1.0f - w) * l1.w + w * h1.w);
        *(bf16x8*)(orow + j * DD) = o;
    }
}

__global__ __launch_bounds__(256) void prep_all(
    const float* __restrict__ feats, const float* __restrict__ rois,
    const float* __restrict__ W_left, const float* __restrict__ W_inner,
    const float* __restrict__ W_roi,
    bf16* __restrict__ Xp, bf16* __restrict__ Wl, bf16* __restrict__ Wi,
    bf16* __restrict__ Wr)
{
    __shared__ float ld[4608];
    int bid = blockIdx.x, tid = threadIdx.x;
    if (bid < 4096) {
        pool_body(feats, rois, Xp, bid, tid);
    } else if (bid < 4608) {
        w_row_body<7, 3584>(W_left, Wl, ld, bid - 4096, tid);
    } else if (bid < 5120) {
        w_row_body<9, 4608>(W_inner, Wi, ld, bid - 4608, tid);
    } else {
        int i0 = (bid - 5120) * 1024 + tid * 4;
        float4 v = *(const float4*)(W_roi + i0);
        bf16* d = Wr + i0;
        d[0] = (bf16)v.x; d[1] = (bf16)v.y; d[2] = (bf16)v.z; d[3] = (bf16)v.w;
    }
}

// ---------------- single GEMM body (r11/r13 proven; NF-templated) ----------------
// BM=64, BN=32*NF; 4 waves (2x2), wave tile 32x(16*NF).  Depth-2 pipeline,
// two buffers; exact counted vmcnt = loads/stage = 2+NF.
template<int K, int NF, bool OUT_BF16>
__device__ __forceinline__ void gemm_single_body(
    const bf16* __restrict__ A, int lda,
    const bf16* __restrict__ Bw, const float* __restrict__ bias,
    void* __restrict__ Out, int ldo, int ocol0,
    bf16* sm, int m0, int n0)
{
    constexpr int BN = 32 * NF;
    int tid = threadIdx.x, lane = tid & 63, w = tid >> 6;
    int wr = w >> 1, wc = w & 1;
    const bf16* Ab = A + (size_t)m0 * lda;
    const bf16* Bb = Bw + (size_t)n0 * K;
    int frow = lane & 15, sl = lane >> 4;
    f32x4 acc[2][NF] = {};
    bf16 *A0 = sm,                 *B0 = sm + 4096;
    bf16 *A1 = sm + 4096 + BN*64,  *B1 = A1 + 4096;

    auto stage = [&](bf16* as, bf16* bs, int t) {   // 2+NF loads/thread
        stage_tile64<64>(Ab + t * 64, lda, as, tid);
        stage_tile64<BN>(Bb + t * 64, K, bs, tid);
    };
    auto step_body = [&](bf16* as, bf16* bs, int t, bool dostage) {
        __builtin_amdgcn_s_barrier();
        bf16x8 af[2][2], bfr[2][NF];
#pragma unroll
        for (int ks = 0; ks < 2; ++ks) {
#pragma unroll
            for (int mf = 0; mf < 2; ++mf) af[ks][mf] = frd64(as, wr * 32 + mf * 16 + frow, ks * 4 + sl);
#pragma unroll
            for (int nf = 0; nf < NF; ++nf) bfr[ks][nf] = frd64(bs, wc * (16*NF) + nf * 16 + frow, ks * 4 + sl);
        }
        asm volatile("s_waitcnt lgkmcnt(0)" ::: "memory");
        __builtin_amdgcn_sched_barrier(0);
        __builtin_amdgcn_s_barrier();
        if (dostage) stage(as, bs, t + 2);
        __builtin_amdgcn_s_setprio(1);
#pragma unroll
        for (int ks = 0; ks < 2; ++ks)
#pragma unroll
            for (int mf = 0; mf < 2; ++mf)
#pragma unroll
                for (int nf = 0; nf < NF; ++nf)
                    acc[mf][nf] = __builtin_amdgcn_mfma_f32_16x16x32_bf16(af[ks][mf], bfr[ks][nf], acc[mf][nf], 0, 0, 0);
        __builtin_amdgcn_s_setprio(0);
    };

    constexpr int NT = K / 64;
    stage(A0, B0, 0);
    stage(A1, B1, 1);
    for (int t = 0; t + 2 < NT; t += 2) {
        wait_vm<2 + NF>(); step_body(A0, B0, t, true);
        wait_vm<2 + NF>(); step_body(A1, B1, t + 1, true);
    }
    wait_vm<2 + NF>(); step_body(A0, B0, NT - 2, false);
    wait_vm<0>();      step_body(A1, B1, NT - 1, false);

    int crow = (lane >> 4) * 4;
    int ccol = lane & 15;
#pragma unroll
    for (int mf = 0; mf < 2; ++mf) {
#pragma unroll
        for (int nf = 0; nf < NF; ++nf) {
            int col = n0 + wc * (16*NF) + nf * 16 + ccol;
            float bv = bias[col];
#pragma unroll
            for (int r2 = 0; r2 < 4; ++r2) {
                int row = m0 + wr * 32 + mf * 16 + crow + r2;
                float v = selu_f(acc[mf][nf][r2] + bv);
                if constexpr (OUT_BF16)
                    ((bf16*)Out)[(size_t)row * ldo + ocol0 + col] = (bf16)v;
                else
                    ((float*)Out)[(size_t)row * ldo + ocol0 + col] = v;
            }
        }
    }
}

// ---------------- dual GEMM body: in-wave L/R stream interleave (r13) ----------------
template<int K>
__device__ __forceinline__ void gemm_dual_body(
    const bf16* __restrict__ Xp, const bf16* __restrict__ Wl,
    const float* __restrict__ bias, bf16* __restrict__ Y,
    bf16* sm, int m0, int n0)
{
    int tid = threadIdx.x, lane = tid & 63, w = tid >> 6;
    int wr = w >> 1, wc = w & 1;
    const bf16* AL = Xp + (size_t)m0 * LDXP;         // bins 0..6
    const bf16* AR = AL + 3072;                      // bins 6..12
    const bf16* Bb = Wl + (size_t)n0 * K;
    int frow = lane & 15, sl = lane >> 4;
    f32x4 accL[2][4] = {}, accR[2][4] = {};
    bf16 *Ls[2] = {sm,         sm + 4096};
    bf16 *Rs[2] = {sm + 8192,  sm + 12288};
    bf16 *Bs[2] = {sm + 16384, sm + 24576};

    bf16x8 fL[2][2][2], fR[2][2][2], fB[2][2][4];    // [set][ks][frag]

    auto stageL  = [&](int t) {                      // 2 loads/thread
        stage_tile64<64>(AL + t * 64, LDXP, Ls[t & 1], tid);
    };
    auto stageRB = [&](int t) {                      // 6 loads/thread
        stage_tile64<64>(AR + t * 64, LDXP, Rs[t & 1], tid);
        stage_tile64<128>(Bb + t * 64, K, Bs[t & 1], tid);
    };
    auto readLB = [&](int t, int s) {                // 12 ds_reads
#pragma unroll
        for (int ks = 0; ks < 2; ++ks) {
#pragma unroll
            for (int nf = 0; nf < 4; ++nf)
                fB[s][ks][nf] = frd64(Bs[t & 1], wc * 64 + nf * 16 + frow, ks * 4 + sl);
#pragma unroll
            for (int mf = 0; mf < 2; ++mf)
                fL[s][ks][mf] = frd64(Ls[t & 1], wr * 32 + mf * 16 + frow, ks * 4 + sl);
        }
    };
    auto readR = [&](int t, int s) {                 // 4 ds_reads
#pragma unroll
        for (int ks = 0; ks < 2; ++ks)
#pragma unroll
            for (int mf = 0; mf < 2; ++mf)
                fR[s][ks][mf] = frd64(Rs[t & 1], wr * 32 + mf * 16 + frow, ks * 4 + sl);
    };
    auto mmaR = [&](int s) {
        __builtin_amdgcn_s_setprio(1);
#pragma unroll
        for (int ks = 0; ks < 2; ++ks)
#pragma unroll
            for (int mf = 0; mf < 2; ++mf)
#pragma unroll
                for (int nf = 0; nf < 4; ++nf)
                    accR[mf][nf] = __builtin_amdgcn_mfma_f32_16x16x32_bf16(fR[s][ks][mf], fB[s][ks][nf], accR[mf][nf], 0, 0, 0);
        __builtin_amdgcn_s_setprio(0);
    };
    auto mmaL = [&](int s) {
        __builtin_amdgcn_s_setprio(1);
#pragma unroll
        for (int ks = 0; ks < 2; ++ks)
#pragma unroll
            for (int mf = 0; mf < 2; ++mf)
#pragma unroll
                for (int nf = 0; nf < 4; ++nf)
                    accL[mf][nf] = __builtin_amdgcn_mfma_f32_16x16x32_bf16(fL[s][ks][mf], fB[s][ks][nf], accL[mf][nf], 0, 0, 0);
        __builtin_amdgcn_s_setprio(0);
    };

    constexpr int NT = K / 64;   // 56 (even)
    stageL(0); stageRB(0); stageL(1); stageRB(1);

    for (int t = 0; t < NT; t += 2) {
        // ---- parity 0: phase A ----
        if (t + 1 < NT) wait_vm<8>(); else wait_vm<0>();
        __builtin_amdgcn_s_barrier();
        readLB(t, 0);
        if (t > 0) mmaR(1);
        asm volatile("s_waitcnt lgkmcnt(0)" ::: "memory");
        __builtin_amdgcn_s_barrier();
        if (t + 2 < NT) stageL(t + 2);
        // ---- parity 0: phase B ----
        readR(t, 0);
        mmaL(0);
        asm volatile("s_waitcnt lgkmcnt(0)" ::: "memory");
        __builtin_amdgcn_s_barrier();
        if (t + 2 < NT) stageRB(t + 2);
        // ---- parity 1: phase A ----
        int t1 = t + 1;
        if (t1 + 1 < NT) wait_vm<8>(); else wait_vm<0>();
        __builtin_amdgcn_s_barrier();
        readLB(t1, 1);
        mmaR(0);
        asm volatile("s_waitcnt lgkmcnt(0)" ::: "memory");
        __builtin_amdgcn_s_barrier();
        if (t1 + 2 < NT) stageL(t1 + 2);
        // ---- parity 1: phase B ----
        readR(t1, 1);
        mmaL(1);
        asm volatile("s_waitcnt lgkmcnt(0)" ::: "memory");
        __builtin_amdgcn_s_barrier();
        if (t1 + 2 < NT) stageRB(t1 + 2);
    }
    mmaR(1);   // finish tile NT-1 (set (NT-1)&1 = 1)

    int crow = (lane >> 4) * 4;
    int ccol = lane & 15;
#pragma unroll
    for (int mf = 0; mf < 2; ++mf) {
#pragma unroll
        for (int nf = 0; nf < 4; ++nf) {
            int col = n0 + wc * 64 + nf * 16 + ccol;
            float bv = bias[col];
#pragma unroll
            for (int r2 = 0; r2 < 4; ++r2) {
                int row = m0 + wr * 32 + mf * 16 + crow + r2;
                float vL = selu_f(accL[mf][nf][r2] + bv);
                float vR = selu_f(accR[mf][nf][r2] + bv);
                Y[(size_t)row * 1024 + col] = (bf16)(vR - vL);
            }
        }
    }
}

// ---------------- GEMM kernels ----------------
// Linear m-major mapping (measured best): dual bids 0..255, inner 256..511.
__global__ __launch_bounds__(256, 2) void wide_gemm(
    const bf16* __restrict__ Xp, const bf16* __restrict__ Wl,
    const float* __restrict__ bl, const bf16* __restrict__ Wi,
    const float* __restrict__ bi, bf16* __restrict__ Y)
{
    __shared__ bf16 sm[32768];  // 64 KB
    int bid = blockIdx.x;
    if (bid < 256) {
        gemm_dual_body<3584>(Xp, Wl, bl, Y, sm, (bid & 63) * 64, (bid >> 6) * 128);
    } else {
        int b2 = bid - 256;
        gemm_single_body<4608, 4, true>(Xp + 1024, LDXP, Wi, bi, (void*)Y, 1024, 512,
                                        sm, (b2 & 63) * 64, (b2 >> 6) * 128);
    }
}

// final: 512 blocks (BM=64, BN=64) -> 2 blocks/CU for cross-block stall
// covering (1 block/CU was the measured-worst config).
__global__ __launch_bounds__(256) void final_gemm(
    const bf16* __restrict__ Y, const bf16* __restrict__ Wr,
    const float* __restrict__ br, float* __restrict__ out)
{
    __shared__ bf16 sm[16384];  // 32 KB
    int bid = blockIdx.x;
    gemm_single_body<1024, 2, false>(Y, 1024, Wr, br, (void*)out, 512, 0,
                                     sm, (bid & 63) * 64, (bid >> 6) * 64);
}

// ---------------- launch ----------------
extern "C" void kernel_launch(void* const* d_in, const int* in_sizes, int n_in,
                              void* d_out, int out_size, void* d_ws, size_t ws_size,
                              hipStream_t stream) {
    const float* feats   = (const float*)d_in[0];
    const float* rois    = (const float*)d_in[3];
    const float* W_left  = (const float*)d_in[6];
    const float* b_left  = (const float*)d_in[7];
    const float* W_inner = (const float*)d_in[8];
    const float* b_inner = (const float*)d_in[9];
    const float* W_roi   = (const float*)d_in[10];
    const float* b_roi   = (const float*)d_in[11];
    float* out = (float*)d_out;

    bf16* wsb = (bf16*)d_ws;
    constexpr size_t XP_ELEMS = (size_t)MM * LDXP;
    constexpr size_t WL_ELEMS = (size_t)512 * 3584;
    constexpr size_t WI_ELEMS = (size_t)512 * 4608;
    constexpr size_t WR_ELEMS = (size_t)512 * 1024;
    bf16* Xp = wsb;
    bf16* Wl = Xp + XP_ELEMS;
    bf16* Wi = Wl + WL_ELEMS;
    bf16* Wr = Wi + WI_ELEMS;
    bf16* Y  = Wr + WR_ELEMS;   // [M][1024]

    prep_all<<<5632, 256, 0, stream>>>(feats, rois, W_left, W_inner, W_roi,
                                       Xp, Wl, Wi, Wr);
    wide_gemm<<<512, 256, 0, stream>>>(Xp, Wl, b_left, Wi, b_inner, Y);
    final_gemm<<<512, 256, 0, stream>>>(Y, Wr, b_roi, out);
}